// Round 1
// baseline (268.589 us; speedup 1.0000x reference)
//
#include <hip/hip_runtime.h>
#include <hip/hip_bf16.h>
#include <stdint.h>

// Problem constants
#define NFEAT 4096   // IN_FEATURES == OUT_FEATURES
#define MROWS 1024   // batch
// K (top-k) = 41, ALPHA_LR = 0.01, NUM_DYKSTRA_ITER = 50

typedef __bf16 bf16x8 __attribute__((ext_vector_type(8)));
typedef float  f32x4  __attribute__((ext_vector_type(4)));

__device__ __forceinline__ unsigned short bf16_rne(float f) {
    unsigned int u = __float_as_uint(f);
    unsigned int r = (u + 0x7fffu + ((u >> 16) & 1u)) >> 16;
    return (unsigned short)r;
}

// ---------------- Kernel 1: Dykstra soft top-k mask on alpha ----------------
// One block, 256 threads, 16 elements per thread held in registers.
// Faithful to reference: p_new computed as yp - (yp - shift) per element.
__global__ __launch_bounds__(256) void dykstra_kernel(const float* __restrict__ alpha,
                                                      float* __restrict__ g) {
    const int tid = threadIdx.x;
    float y[16], p[16], q[16], yp[16];
    #pragma unroll
    for (int j = 0; j < 16; ++j) {
        y[j] = alpha[tid + 256 * j] / 0.01f;   // y0 = x / l
        p[j] = 0.0f;
        q[j] = 0.0f;
    }
    __shared__ float red[4];
    for (int it = 0; it < 50; ++it) {
        float s = 0.0f;
        #pragma unroll
        for (int j = 0; j < 16; ++j) { yp[j] = y[j] + p[j]; s += yp[j]; }
        #pragma unroll
        for (int off = 32; off > 0; off >>= 1) s += __shfl_down(s, off, 64);
        if ((tid & 63) == 0) red[tid >> 6] = s;
        __syncthreads();
        const float S = (red[0] + red[1]) + (red[2] + red[3]);
        __syncthreads();
        const float shift = (S - 41.0f) / 4096.0f;  // (sum - k) / n
        #pragma unroll
        for (int j = 0; j < 16; ++j) {
            float y_hp = yp[j] - shift;
            p[j] = yp[j] - y_hp;                // NOT folded to 'shift' (fp semantics)
            float yq = y_hp + q[j];
            float yb = fminf(fmaxf(yq, 0.0f), 1.0f);
            q[j] = yq - yb;
            y[j] = yb;
        }
    }
    #pragma unroll
    for (int j = 0; j < 16; ++j) g[tid + 256 * j] = y[j];
}

// ---------------- Kernel 2: materialize W in bf16 ----------------
// W[r,c] = g[(r-c)%n] * V[(r-c)%n, c].  64x64 output tile per block.
// Load V rows i0..i0+127 (the tile's diagonal band) coalesced into LDS,
// then read anti-diagonally (row stride 64 floats -> bank delta -63 === 1 mod 32,
// conflict-free), write W coalesced.
__global__ __launch_bounds__(256) void build_w_kernel(const float* __restrict__ V,
                                                      const float* __restrict__ g,
                                                      unsigned short* __restrict__ Wb) {
    __shared__ float vt[128 * 64];
    __shared__ float gl[128];
    const int tid = threadIdx.x;
    const int c0 = blockIdx.x * 64;
    const int r0 = blockIdx.y * 64;
    const int i0 = (r0 - c0 - 63) & 4095;
    #pragma unroll
    for (int j = 0; j < 8; ++j) {
        int idx = tid + 256 * j;        // 2048 float4 chunks = 128 rows x 16 float4
        int t   = idx >> 4;
        int col = (idx & 15) << 2;
        int i   = (i0 + t) & 4095;
        *(float4*)(vt + t * 64 + col) = *(const float4*)(V + (size_t)i * NFEAT + c0 + col);
    }
    if (tid < 128) gl[tid] = g[(i0 + tid) & 4095];
    __syncthreads();
    const int dc  = tid & 63;   // lane -> column (coalesced writes)
    const int drb = tid >> 6;
    #pragma unroll
    for (int j = 0; j < 16; ++j) {
        int dr = drb + 4 * j;                    // row within tile, uniform per wave
        int t  = dr - dc + 63;                   // in [0,126]
        float wv = gl[t] * vt[t * 64 + dc];
        Wb[(size_t)(r0 + dr) * NFEAT + c0 + dc] = bf16_rne(wv);
    }
}

// ---------------- Kernel 3: x fp32 -> bf16 (RNE) ----------------
__global__ __launch_bounds__(256) void cvt_x_kernel(const float* __restrict__ x,
                                                    unsigned short* __restrict__ xb) {
    const size_t i = (size_t)(blockIdx.x * 256 + threadIdx.x) * 8;
    float4 a = *(const float4*)(x + i);
    float4 b = *(const float4*)(x + i + 4);
    uint4 st;
    st.x = bf16_rne(a.x) | ((unsigned)bf16_rne(a.y) << 16);
    st.y = bf16_rne(a.z) | ((unsigned)bf16_rne(a.w) << 16);
    st.z = bf16_rne(b.x) | ((unsigned)bf16_rne(b.y) << 16);
    st.w = bf16_rne(b.z) | ((unsigned)bf16_rne(b.w) << 16);
    *(uint4*)(xb + i) = st;
}

// ---------------- Kernel 4: GEMM C[m,n] = sum_k A[m,k] * B[n,k] ----------------
// A = xb (1024x4096 bf16), B = Wb (4096x4096 bf16, row-major = B^T layout), C fp32.
// 128x128 tile, BK=32, 256 threads = 4 waves in 2x2, each wave 64x64 via
// 4x4 mfma_f32_16x16x32_bf16.  global_load_lds width=16 into LDS layout
// [kgroup(4)][row(128)][8 bf16] so each ds_read_b128 is one MFMA fragment.
__global__ __launch_bounds__(256) void gemm_kernel(const unsigned short* __restrict__ A,
                                                   const unsigned short* __restrict__ B,
                                                   float* __restrict__ C) {
    __shared__ unsigned short As[4096];   // 8 KB
    __shared__ unsigned short Bs[4096];   // 8 KB
    const int tid  = threadIdx.x;
    const int lane = tid & 63;
    const int w    = tid >> 6;
    const int wm   = w & 1;
    const int wn   = w >> 1;
    const int m0   = blockIdx.y * 128;
    const int n0   = blockIdx.x * 128;

    f32x4 acc[4][4];
    #pragma unroll
    for (int i = 0; i < 4; ++i)
        #pragma unroll
        for (int j = 0; j < 4; ++j)
            acc[i][j] = (f32x4){0.f, 0.f, 0.f, 0.f};

    // Global sources for this wave's staging chunks: chunk = (kgroup=w, mhalf)
    const unsigned short* aS0 = A + (size_t)(m0 + lane) * NFEAT + w * 8;
    const unsigned short* aS1 = A + (size_t)(m0 + 64 + lane) * NFEAT + w * 8;
    const unsigned short* bS0 = B + (size_t)(n0 + lane) * NFEAT + w * 8;
    const unsigned short* bS1 = B + (size_t)(n0 + 64 + lane) * NFEAT + w * 8;
    unsigned short* aD0 = As + w * 1024;         // kg=w, rows 0..63
    unsigned short* aD1 = As + w * 1024 + 512;   // kg=w, rows 64..127
    unsigned short* bD0 = Bs + w * 1024;
    unsigned short* bD1 = Bs + w * 1024 + 512;

    const int kg = lane >> 4;
    const int lm = lane & 15;
    const unsigned short* aRd = As + kg * 1024 + (wm * 64 + lm) * 8;
    const unsigned short* bRd = Bs + kg * 1024 + (wn * 64 + lm) * 8;

    for (int kt = 0; kt < 128; ++kt) {
        const int ko = kt * 32;
        __syncthreads();
        __builtin_amdgcn_global_load_lds((__attribute__((address_space(1))) void*)(aS0 + ko),
                                         (__attribute__((address_space(3))) void*)aD0, 16, 0, 0);
        __builtin_amdgcn_global_load_lds((__attribute__((address_space(1))) void*)(aS1 + ko),
                                         (__attribute__((address_space(3))) void*)aD1, 16, 0, 0);
        __builtin_amdgcn_global_load_lds((__attribute__((address_space(1))) void*)(bS0 + ko),
                                         (__attribute__((address_space(3))) void*)bD0, 16, 0, 0);
        __builtin_amdgcn_global_load_lds((__attribute__((address_space(1))) void*)(bS1 + ko),
                                         (__attribute__((address_space(3))) void*)bD1, 16, 0, 0);
        __syncthreads();

        bf16x8 af[4], bfv[4];
        #pragma unroll
        for (int mi = 0; mi < 4; ++mi) af[mi]  = *(const bf16x8*)(aRd + mi * 128);
        #pragma unroll
        for (int ni = 0; ni < 4; ++ni) bfv[ni] = *(const bf16x8*)(bRd + ni * 128);
        #pragma unroll
        for (int mi = 0; mi < 4; ++mi)
            #pragma unroll
            for (int ni = 0; ni < 4; ++ni)
                acc[mi][ni] = __builtin_amdgcn_mfma_f32_16x16x32_bf16(af[mi], bfv[ni],
                                                                      acc[mi][ni], 0, 0, 0);
    }

    // Epilogue: C/D layout col = lane&15, row = (lane>>4)*4 + reg  (m89-verified)
    const int crow = m0 + wm * 64 + (lane >> 4) * 4;
    const int ccol = n0 + wn * 64 + lm;
    #pragma unroll
    for (int mi = 0; mi < 4; ++mi)
        #pragma unroll
        for (int ni = 0; ni < 4; ++ni) {
            float* cp = C + (size_t)(crow + mi * 16) * NFEAT + ccol + ni * 16;
            #pragma unroll
            for (int r = 0; r < 4; ++r)
                cp[(size_t)r * NFEAT] = acc[mi][ni][r];
        }
}

extern "C" void kernel_launch(void* const* d_in, const int* in_sizes, int n_in,
                              void* d_out, int out_size, void* d_ws, size_t ws_size,
                              hipStream_t stream) {
    const float* x     = (const float*)d_in[0];   // (1024, 4096) fp32
    const float* V     = (const float*)d_in[1];   // (4096, 4096) fp32
    const float* alpha = (const float*)d_in[2];   // (4096,) fp32
    float* out = (float*)d_out;                   // (1024, 4096) fp32

    char* ws = (char*)d_ws;
    float* g           = (float*)ws;                                      // 16 KB
    unsigned short* xb = (unsigned short*)(ws + 16384);                   // 8 MB
    unsigned short* Wb = (unsigned short*)(ws + 16384 + (size_t)MROWS * NFEAT * 2); // 32 MB

    hipLaunchKernelGGL(dykstra_kernel, dim3(1),      dim3(256), 0, stream, alpha, g);
    hipLaunchKernelGGL(cvt_x_kernel,   dim3(2048),   dim3(256), 0, stream, x, xb);
    hipLaunchKernelGGL(build_w_kernel, dim3(64, 64), dim3(256), 0, stream, V, g, Wb);
    hipLaunchKernelGGL(gemm_kernel,    dim3(32, 8),  dim3(256), 0, stream, xb, Wb, out);
}

// Round 2
// 233.230 us; speedup vs baseline: 1.1516x; 1.1516x over previous
//
#include <hip/hip_runtime.h>
#include <hip/hip_bf16.h>
#include <stdint.h>

// Problem constants
#define NFEAT 4096   // IN_FEATURES == OUT_FEATURES
#define MROWS 1024   // batch
// K (top-k) = 41, ALPHA_LR = 0.01, NUM_DYKSTRA_ITER = 50

typedef __bf16 bf16x8 __attribute__((ext_vector_type(8)));
typedef float  f32x4  __attribute__((ext_vector_type(4)));

__device__ __forceinline__ unsigned short bf16_rne(float f) {
    unsigned int u = __float_as_uint(f);
    unsigned int r = (u + 0x7fffu + ((u >> 16) & 1u)) >> 16;
    return (unsigned short)r;
}

// ---------------- Kernel 1: Dykstra soft top-k mask on alpha ----------------
__global__ __launch_bounds__(256) void dykstra_kernel(const float* __restrict__ alpha,
                                                      float* __restrict__ g) {
    const int tid = threadIdx.x;
    float y[16], p[16], q[16], yp[16];
    #pragma unroll
    for (int j = 0; j < 16; ++j) {
        y[j] = alpha[tid + 256 * j] / 0.01f;   // y0 = x / l
        p[j] = 0.0f;
        q[j] = 0.0f;
    }
    __shared__ float red[4];
    for (int it = 0; it < 50; ++it) {
        float s = 0.0f;
        #pragma unroll
        for (int j = 0; j < 16; ++j) { yp[j] = y[j] + p[j]; s += yp[j]; }
        #pragma unroll
        for (int off = 32; off > 0; off >>= 1) s += __shfl_down(s, off, 64);
        if ((tid & 63) == 0) red[tid >> 6] = s;
        __syncthreads();
        const float S = (red[0] + red[1]) + (red[2] + red[3]);
        __syncthreads();
        const float shift = (S - 41.0f) / 4096.0f;  // (sum - k) / n
        #pragma unroll
        for (int j = 0; j < 16; ++j) {
            float y_hp = yp[j] - shift;
            p[j] = yp[j] - y_hp;                // NOT folded to 'shift' (fp semantics)
            float yq = y_hp + q[j];
            float yb = fminf(fmaxf(yq, 0.0f), 1.0f);
            q[j] = yq - yb;
            y[j] = yb;
        }
    }
    #pragma unroll
    for (int j = 0; j < 16; ++j) g[tid + 256 * j] = y[j];
}

// ---------------- Kernel 2: materialize W in bf16 ----------------
// W[r,c] = g[(r-c)%n] * V[(r-c)%n, c].  64x64 output tile per block.
__global__ __launch_bounds__(256) void build_w_kernel(const float* __restrict__ V,
                                                      const float* __restrict__ g,
                                                      unsigned short* __restrict__ Wb) {
    __shared__ float vt[128 * 64];
    __shared__ float gl[128];
    const int tid = threadIdx.x;
    const int c0 = blockIdx.x * 64;
    const int r0 = blockIdx.y * 64;
    const int i0 = (r0 - c0 - 63) & 4095;
    #pragma unroll
    for (int j = 0; j < 8; ++j) {
        int idx = tid + 256 * j;        // 2048 float4 chunks = 128 rows x 16 float4
        int t   = idx >> 4;
        int col = (idx & 15) << 2;
        int i   = (i0 + t) & 4095;
        *(float4*)(vt + t * 64 + col) = *(const float4*)(V + (size_t)i * NFEAT + c0 + col);
    }
    if (tid < 128) gl[tid] = g[(i0 + tid) & 4095];
    __syncthreads();
    const int dc  = tid & 63;   // lane -> column (coalesced writes)
    const int drb = tid >> 6;
    #pragma unroll
    for (int j = 0; j < 16; ++j) {
        int dr = drb + 4 * j;                    // row within tile, uniform per wave
        int t  = dr - dc + 63;                   // in [0,126]
        float wv = gl[t] * vt[t * 64 + dc];
        Wb[(size_t)(r0 + dr) * NFEAT + c0 + dc] = bf16_rne(wv);
    }
}

// ---------------- Kernel 3: x fp32 -> bf16 (RNE) ----------------
__global__ __launch_bounds__(256) void cvt_x_kernel(const float* __restrict__ x,
                                                    unsigned short* __restrict__ xb) {
    const size_t i = (size_t)(blockIdx.x * 256 + threadIdx.x) * 8;
    float4 a = *(const float4*)(x + i);
    float4 b = *(const float4*)(x + i + 4);
    uint4 st;
    st.x = bf16_rne(a.x) | ((unsigned)bf16_rne(a.y) << 16);
    st.y = bf16_rne(a.z) | ((unsigned)bf16_rne(a.w) << 16);
    st.z = bf16_rne(b.x) | ((unsigned)bf16_rne(b.y) << 16);
    st.w = bf16_rne(b.z) | ((unsigned)bf16_rne(b.w) << 16);
    *(uint4*)(xb + i) = st;
}

// ---------------- Kernel 4: split-K GEMM  C_z = A * B^T over K slice z ------
// A = xb (1024x4096 bf16), B = Wb (4096x4096 bf16 row-major), partials fp32.
// 128x128 tile, BK=32, 256 threads = 4 waves (2x2), wave does 64x64 via 4x4
// mfma_f32_16x16x32_bf16. global_load_lds width=16, LDS [kgroup(4)][row(128)][8].
// blockIdx.z = K-slice; slice 0 writes d_out, slice s>0 writes Cp[s-1].
__global__ __launch_bounds__(256) void gemm_kernel(const unsigned short* __restrict__ A,
                                                   const unsigned short* __restrict__ B,
                                                   float* __restrict__ C0,
                                                   float* __restrict__ Cp,
                                                   int kiters) {
    __shared__ unsigned short As[4096];   // 8 KB
    __shared__ unsigned short Bs[4096];   // 8 KB
    const int tid  = threadIdx.x;
    const int lane = tid & 63;
    const int w    = tid >> 6;
    const int wm   = w & 1;
    const int wn   = w >> 1;
    const int m0   = blockIdx.y * 128;
    const int n0   = blockIdx.x * 128;
    const int kz   = blockIdx.z;
    const int kbase = kz * kiters * 32;

    f32x4 acc[4][4];
    #pragma unroll
    for (int i = 0; i < 4; ++i)
        #pragma unroll
        for (int j = 0; j < 4; ++j)
            acc[i][j] = (f32x4){0.f, 0.f, 0.f, 0.f};

    const unsigned short* aS0 = A + (size_t)(m0 + lane) * NFEAT + kbase + w * 8;
    const unsigned short* aS1 = A + (size_t)(m0 + 64 + lane) * NFEAT + kbase + w * 8;
    const unsigned short* bS0 = B + (size_t)(n0 + lane) * NFEAT + kbase + w * 8;
    const unsigned short* bS1 = B + (size_t)(n0 + 64 + lane) * NFEAT + kbase + w * 8;
    unsigned short* aD0 = As + w * 1024;         // kg=w, rows 0..63
    unsigned short* aD1 = As + w * 1024 + 512;   // kg=w, rows 64..127
    unsigned short* bD0 = Bs + w * 1024;
    unsigned short* bD1 = Bs + w * 1024 + 512;

    const int kg = lane >> 4;
    const int lm = lane & 15;
    const unsigned short* aRd = As + kg * 1024 + (wm * 64 + lm) * 8;
    const unsigned short* bRd = Bs + kg * 1024 + (wn * 64 + lm) * 8;

    for (int kt = 0; kt < kiters; ++kt) {
        const int ko = kt * 32;
        __syncthreads();
        __builtin_amdgcn_global_load_lds((__attribute__((address_space(1))) void*)(aS0 + ko),
                                         (__attribute__((address_space(3))) void*)aD0, 16, 0, 0);
        __builtin_amdgcn_global_load_lds((__attribute__((address_space(1))) void*)(aS1 + ko),
                                         (__attribute__((address_space(3))) void*)aD1, 16, 0, 0);
        __builtin_amdgcn_global_load_lds((__attribute__((address_space(1))) void*)(bS0 + ko),
                                         (__attribute__((address_space(3))) void*)bD0, 16, 0, 0);
        __builtin_amdgcn_global_load_lds((__attribute__((address_space(1))) void*)(bS1 + ko),
                                         (__attribute__((address_space(3))) void*)bD1, 16, 0, 0);
        __syncthreads();

        bf16x8 af[4], bfv[4];
        #pragma unroll
        for (int mi = 0; mi < 4; ++mi) af[mi]  = *(const bf16x8*)(aRd + mi * 128);
        #pragma unroll
        for (int ni = 0; ni < 4; ++ni) bfv[ni] = *(const bf16x8*)(bRd + ni * 128);
        #pragma unroll
        for (int mi = 0; mi < 4; ++mi)
            #pragma unroll
            for (int ni = 0; ni < 4; ++ni)
                acc[mi][ni] = __builtin_amdgcn_mfma_f32_16x16x32_bf16(af[mi], bfv[ni],
                                                                      acc[mi][ni], 0, 0, 0);
    }

    float* Cz = (kz == 0) ? C0 : (Cp + (size_t)(kz - 1) * MROWS * NFEAT);
    // C/D layout: col = lane&15, row = (lane>>4)*4 + reg  (m89-verified)
    const int crow = m0 + wm * 64 + (lane >> 4) * 4;
    const int ccol = n0 + wn * 64 + lm;
    #pragma unroll
    for (int mi = 0; mi < 4; ++mi)
        #pragma unroll
        for (int ni = 0; ni < 4; ++ni) {
            float* cp = Cz + (size_t)(crow + mi * 16) * NFEAT + ccol + ni * 16;
            #pragma unroll
            for (int r = 0; r < 4; ++r)
                cp[(size_t)r * NFEAT] = acc[mi][ni][r];
        }
}

// ---------------- Kernel 5: split-K reduce: out += sum of partials ----------
__global__ __launch_bounds__(256) void reduce_kernel(float* __restrict__ out,
                                                     const float* __restrict__ Cp,
                                                     int nparts) {
    const size_t i = (size_t)(blockIdx.x * 256 + threadIdx.x) * 4;
    float4 a = *(const float4*)(out + i);
    for (int s = 0; s < nparts; ++s) {
        float4 b = *(const float4*)(Cp + (size_t)s * MROWS * NFEAT + i);
        a.x += b.x; a.y += b.y; a.z += b.z; a.w += b.w;
    }
    *(float4*)(out + i) = a;
}

extern "C" void kernel_launch(void* const* d_in, const int* in_sizes, int n_in,
                              void* d_out, int out_size, void* d_ws, size_t ws_size,
                              hipStream_t stream) {
    const float* x     = (const float*)d_in[0];   // (1024, 4096) fp32
    const float* V     = (const float*)d_in[1];   // (4096, 4096) fp32
    const float* alpha = (const float*)d_in[2];   // (4096,) fp32
    float* out = (float*)d_out;                   // (1024, 4096) fp32

    char* ws = (char*)d_ws;
    const size_t g_off  = 0;
    const size_t xb_off = 16384;
    const size_t wb_off = xb_off + (size_t)MROWS * NFEAT * 2;   //  8 MB after
    const size_t cp_off = wb_off + (size_t)NFEAT * NFEAT * 2;   // 32 MB after
    float* g           = (float*)(ws + g_off);
    unsigned short* xb = (unsigned short*)(ws + xb_off);
    unsigned short* Wb = (unsigned short*)(ws + wb_off);
    float* Cp          = (float*)(ws + cp_off);

    // Split-K factor chosen from available workspace (constant across calls).
    const size_t part_bytes = (size_t)MROWS * NFEAT * 4;        // 16 MB each
    int S = 1;
    if (ws_size >= cp_off + 3 * part_bytes) S = 4;
    else if (ws_size >= cp_off + 1 * part_bytes) S = 2;
    const int kiters = 128 / S;   // K-iterations (BK=32) per slice

    hipLaunchKernelGGL(dykstra_kernel, dim3(1),        dim3(256), 0, stream, alpha, g);
    hipLaunchKernelGGL(cvt_x_kernel,   dim3(2048),     dim3(256), 0, stream, x, xb);
    hipLaunchKernelGGL(build_w_kernel, dim3(64, 64),   dim3(256), 0, stream, V, g, Wb);
    hipLaunchKernelGGL(gemm_kernel,    dim3(32, 8, S), dim3(256), 0, stream, xb, Wb, out, Cp, kiters);
    if (S > 1)
        hipLaunchKernelGGL(reduce_kernel, dim3(MROWS * NFEAT / (256 * 4)), dim3(256), 0, stream,
                           out, Cp, S - 1);
}